// Round 11
// baseline (2127.012 us; speedup 1.0000x reference)
//
#include <hip/hip_runtime.h>
#include <stdint.h>

#define T_STEPS 256
#define EMBD 10
#define MB 16          // batch rows per block
#define NBLK 64        // 1024 / MB
#define NKIT 9         // K = 288 = 9 * 32 (256 h + 10 x + 1 bias + pad)

typedef __attribute__((ext_vector_type(8))) short bf16x8;
typedef __attribute__((ext_vector_type(4))) float f32x4;
typedef __attribute__((ext_vector_type(4))) int   i32x4;

__device__ __forceinline__ unsigned short f2bf(float f) {
    union { float f; unsigned int u; } v; v.f = f;
    unsigned int u = v.u;
    unsigned int r = (u + 0x7FFFu + ((u >> 16) & 1u)) >> 16;  // RNE
    return (unsigned short)r;
}
__device__ __forceinline__ float sig_fast(float x) {
    return __frcp_rn(1.0f + exp2f(-1.4426950408889634f * x));
}
__device__ __forceinline__ float tanh_fast(float x) {
    return 1.0f - 2.0f * __frcp_rn(exp2f(2.8853900817779268f * x) + 1.0f);
}

// Park a loaded frag in AGPRs -- storage the VGPR allocator cannot restream
// (R2/R4/R6/R8 all silently re-streamed VGPR-resident B at the ~29 B/cyc
// per-CU L2 latency ceiling). Scalar "=a"/"v" constraints only (128-bit
// tied/indirect constraints are rejected by the backend -- R5/R7).
// volatile: pins the write in the prologue so load+park can't sink into loop.
__device__ __forceinline__ i32x4 park_agpr(i32x4 v) {
    i32x4 r;
    asm volatile("v_accvgpr_write_b32 %0, %4\n\t"
                 "v_accvgpr_write_b32 %1, %5\n\t"
                 "v_accvgpr_write_b32 %2, %6\n\t"
                 "v_accvgpr_write_b32 %3, %7"
                 : "=a"(r.x), "=a"(r.y), "=a"(r.z), "=a"(r.w)
                 : "v"(v.x), "v"(v.y), "v"(v.z), "v"(v.w));
    return r;
}
// Unpark for use. s_nop 1 covers the VALU-write -> MFMA-read 2-wait-state
// hazard even if the builtin MFMA is scheduled immediately after (the
// compiler cannot see inside this asm to insert them itself). All MFMAs are
// BUILTINS -- every other hazard/waitcnt is compiler-managed (no asm MFMA,
// which NaN'd in R9/R10 for reasons invisible without disasm).
__device__ __forceinline__ i32x4 unpark_agpr(i32x4 a) {
    i32x4 r;
    asm("v_accvgpr_read_b32 %0, %4\n\t"
        "v_accvgpr_read_b32 %1, %5\n\t"
        "v_accvgpr_read_b32 %2, %6\n\t"
        "v_accvgpr_read_b32 %3, %7\n\t"
        "s_nop 1"
        : "=v"(r.x), "=v"(r.y), "=v"(r.z), "=v"(r.w)
        : "a"(a.x), "a"(a.y), "a"(a.z), "a"(a.w));
    return r;
}
__device__ __forceinline__ f32x4 mfma_v(i32x4 a, i32x4 b, f32x4 c) {
    return __builtin_amdgcn_mfma_f32_16x16x32_bf16(
        __builtin_bit_cast(bf16x8, a), __builtin_bit_cast(bf16x8, b), c, 0, 0, 0);
}

// ---------------------------------------------------------------------------
// K1: swizzled bf16 weights Wfull[288][1024] in MFMA B-frag order.
// Layout: [kit 0..8][ntile 0..63][lane 0..63] x 16B.
// Lane's 8 bf16: Wfull[k = kit*32 + (lane>>4)*8 + j][n = ntile*16 + (lane&15)]
// k<256 -> Wh[k][:], 256..265 -> Wx[k-256][:], 266 -> bias, else 0.
// ---------------------------------------------------------------------------
__global__ __launch_bounds__(64) void build_wswz(
    const float* __restrict__ Wgx, const float* __restrict__ Wgh, const float* __restrict__ bg,
    const float* __restrict__ Wix, const float* __restrict__ Wih, const float* __restrict__ bi,
    const float* __restrict__ Wfx, const float* __restrict__ Wfh, const float* __restrict__ bf_,
    const float* __restrict__ Wox, const float* __restrict__ Woh, const float* __restrict__ bo,
    unsigned short* __restrict__ wswz)
{
    int g   = blockIdx.x / NKIT;   // ntile
    int kit = blockIdx.x % NKIT;
    int lane = threadIdx.x;
    int n = g * 16 + (lane & 15);
    int q = n >> 8;
    int col = n & 255;
    const float* Wh = (q == 0) ? Wgh : (q == 1) ? Wih : (q == 2) ? Wfh : Woh;
    const float* Wx = (q == 0) ? Wgx : (q == 1) ? Wix : (q == 2) ? Wfx : Wox;
    const float* bb = (q == 0) ? bg  : (q == 1) ? bi  : (q == 2) ? bf_ : bo;
    int k0 = kit * 32 + (lane >> 4) * 8;

    int4 out;
    unsigned short* p = (unsigned short*)&out;
#pragma unroll
    for (int j = 0; j < 8; j++) {
        int k = k0 + j;
        float v = 0.0f;
        if (k < 256)             v = Wh[k * 256 + col];
        else if (k < 256 + EMBD) v = Wx[(k - 256) * 256 + col];
        else if (k == 266)       v = bb[col];
        p[j] = f2bf(v);
    }
    ((int4*)wswz)[(kit * 64 + g) * 64 + lane] = out;
}

// ---------------------------------------------------------------------------
// K2: persistent LSTM. 64 blocks x 256 threads (4 waves, 1 wave/SIMD,
// waves_per_eu(1,1) -> 512 unified regs/wave: 256 arch + 256 AGPR).
// Wave w owns cp = 4w+p (p=0..3) = hcols [64w,64w+64) x 4 gates = 16 N-tiles.
// B residency/wave: kits {0,1,2,3} PARKED in AGPRs (64 frags = 256 AGPR),
// kit {8} in arch VGPRs (64 regs), kits {5,7} in LDS (128 KB),
// kits {4,6} streamed per step (128 KB/step/CU), one-pass-ahead prefetch.
// A-tile (16x288, A-frag order) double-buffered in LDS; ONE barrier/step.
// ---------------------------------------------------------------------------
__global__ __launch_bounds__(256)
__attribute__((amdgpu_waves_per_eu(1, 1)))
void lstm_main(
    const int*   __restrict__ xtok,   // [1024][1][256]
    const float* __restrict__ emb,    // [32000][10]
    const float* __restrict__ Wph,    // [256][10]
    const float* __restrict__ bp,     // [10]
    const unsigned short* __restrict__ wswz,
    float* __restrict__ out)          // [1024][10]
{
    __shared__ __align__(16) unsigned short A_lds[2][8 * 64 * 8];   // 16 KB (kits 0-7)
    __shared__ __align__(16) unsigned short A8_lds[2][64 * 8];      // 2 KB (kit 8)
    __shared__ __align__(16) i32x4 B_lds[2 * 64 * 64];              // 128 KB (kits 5,7)
    __shared__ float outacc[MB * 10];

    const int tid  = threadIdx.x;
    const int w    = tid >> 6;        // wave 0..3
    const int lane = tid & 63;
    const int quad = lane >> 4;
    const int l15  = lane & 15;
    const int blk  = blockIdx.x;

    const int m_x = tid >> 4;         // x-gather: batch row 0..15
    const int e_x = tid & 15;         // emb element (valid if <10)

    const i32x4* Bg = (const i32x4*)wswz;

    // --- prologue: LDS B-cache (kit 5 -> slot 0, kit 7 -> slot 1) ---
    for (int i = tid; i < 64 * 64; i += 256) {
        B_lds[i]        = Bg[5 * 4096 + i];
        B_lds[4096 + i] = Bg[7 * 4096 + i];
    }

    // --- AGPR-parked B: kits 0..3, [kit][gate][p] = 64 frags = 256 AGPR ---
    i32x4 bag[4][4][4];
#pragma unroll
    for (int s = 0; s < 4; s++)
#pragma unroll
        for (int g = 0; g < 4; g++)
#pragma unroll
            for (int p = 0; p < 4; p++)
                bag[s][g][p] = park_agpr(
                    Bg[(s * 64 + g * 16 + 4 * w + p) * 64 + lane]);

    // --- arch-VGPR-resident B: kit 8, [gate][p] ---
    i32x4 b8[4][4];
#pragma unroll
    for (int g = 0; g < 4; g++)
#pragma unroll
        for (int p = 0; p < 4; p++)
            b8[g][p] = Bg[(8 * 64 + g * 16 + 4 * w + p) * 64 + lane];

    // --- init A double buffer: zeros, bias row (both), x_0 (buf 0) ---
    {
        int4 z4 = {0, 0, 0, 0};
        for (int i = tid; i < 1024; i += 256) ((int4*)A_lds)[i] = z4;
        if (tid < 128) ((int4*)A8_lds)[tid] = z4;
    }
    __syncthreads();
    if (tid < 16) {
        // kit8 local k=10 (bias=1.0): lp = m+16, elem 2
        A8_lds[0][(16 + tid) * 8 + 2] = 0x3F80;
        A8_lds[1][(16 + tid) * 8 + 2] = 0x3F80;
    }
    if (e_x < EMBD) {
        int tok = xtok[(blk * MB + m_x) * T_STEPS + 0];
        float v = emb[tok * EMBD + e_x];
        A8_lds[0][(m_x + 16 * (e_x >> 3)) * 8 + (e_x & 7)] = f2bf(v);
    }
    __syncthreads();

    float c[4][4];
#pragma unroll
    for (int p = 0; p < 4; p++)
#pragma unroll
        for (int r = 0; r < 4; r++) c[p][r] = 0.0f;

    for (int t = 0; t < T_STEPS; t++) {
        const i32x4* Ab  = (const i32x4*)A_lds[t & 1];
        const i32x4* A8b = (const i32x4*)A8_lds[t & 1];
        unsigned short* Aw  = A_lds[(t + 1) & 1];
        unsigned short* A8w = A8_lds[(t + 1) & 1];

        // x(t+1) prefetch (independent; overlaps MFMA)
        float xval = 0.0f;
        const bool do_x = (t < T_STEPS - 1) && (e_x < EMBD);
        if (t < T_STEPS - 1) {
            int tok = xtok[(blk * MB + m_x) * T_STEPS + (t + 1)];
            if (e_x < EMBD) xval = emb[tok * EMBD + e_x];
        }

        // A-frags for this step, reused across all 4 passes (36 regs)
        i32x4 aA[9];
#pragma unroll
        for (int k = 0; k < 8; k++) aA[k] = Ab[k * 64 + lane];
        aA[8] = A8b[lane];

        // streamed kits 4 (land[0..3]) and 6 (land[4..7]): prefetch pass 0
        i32x4 land[8];
#pragma unroll
        for (int g = 0; g < 4; g++) {
            land[g]     = Bg[(4 * 64 + g * 16 + 4 * w) * 64 + lane];
            land[4 + g] = Bg[(6 * 64 + g * 16 + 4 * w) * 64 + lane];
        }

#pragma unroll
        for (int p = 0; p < 4; p++) {
            const int cp = 4 * w + p;

            // prefetch next pass's streamed kits (init from land: no poison)
            i32x4 nland[8];
#pragma unroll
            for (int g = 0; g < 8; g++) nland[g] = land[g];
            if (p < 3) {
#pragma unroll
                for (int g = 0; g < 4; g++) {
                    nland[g]     = Bg[(4 * 64 + g * 16 + cp + 1) * 64 + lane];
                    nland[4 + g] = Bg[(6 * 64 + g * 16 + cp + 1) * 64 + lane];
                }
            }

            f32x4 acc[4];
#pragma unroll
            for (int g = 0; g < 4; g++) acc[g] = (f32x4){0.f, 0.f, 0.f, 0.f};

            // kit 8 (resident VGPR)
#pragma unroll
            for (int g = 0; g < 4; g++)
                acc[g] = mfma_v(aA[8], b8[g][p], acc[g]);
            // kits 0..3 (AGPR-parked, unparked per use)
#pragma unroll
            for (int s = 0; s < 4; s++)
#pragma unroll
                for (int g = 0; g < 4; g++)
                    acc[g] = mfma_v(aA[s], unpark_agpr(bag[s][g][p]), acc[g]);
            // kit 5 (LDS)
#pragma unroll
            for (int g = 0; g < 4; g++)
                acc[g] = mfma_v(aA[5], B_lds[(g * 16 + cp) * 64 + lane], acc[g]);
            // kit 4 (streamed)
#pragma unroll
            for (int g = 0; g < 4; g++)
                acc[g] = mfma_v(aA[4], land[g], acc[g]);
            // kit 6 (streamed)
#pragma unroll
            for (int g = 0; g < 4; g++)
                acc[g] = mfma_v(aA[6], land[4 + g], acc[g]);
            // kit 7 (LDS)
#pragma unroll
            for (int g = 0; g < 4; g++)
                acc[g] = mfma_v(aA[7], B_lds[4096 + (g * 16 + cp) * 64 + lane], acc[g]);

            // gate math: z[m][n], m = quad*4+r, n = gate*256 + cp*16 + l15
            const int hcol = cp * 16 + l15;
            const int lpbase = 16 * ((hcol >> 3) & 3);
            const int kofs = (hcol >> 5) * 64;
#pragma unroll
            for (int r = 0; r < 4; r++) {
                float gg = tanh_fast(acc[0][r]);
                float ii = sig_fast(acc[1][r]);
                float ff = sig_fast(acc[2][r]);
                float oo = sig_fast(acc[3][r]);
                float cn = gg * ii + c[p][r] * ff;
                c[p][r] = cn;
                float hh = tanh_fast(cn) * oo;
                int m = quad * 4 + r;
                Aw[(kofs + m + lpbase) * 8 + (hcol & 7)] = f2bf(hh);
            }
#pragma unroll
            for (int g = 0; g < 8; g++) land[g] = nland[g];
        }

        if (t == T_STEPS - 1) break;
        if (do_x)
            A8w[(m_x + 16 * (e_x >> 3)) * 8 + (e_x & 7)] = f2bf(xval);
        __syncthreads();  // single barrier: A(t+1) complete
    }

    // --- epilogue: re-read own h (bf16) from final A buffer, project ---
    const unsigned short* Af = A_lds[T_STEPS & 1];
    float part[4][10];
#pragma unroll
    for (int r = 0; r < 4; r++)
#pragma unroll
        for (int cl = 0; cl < 10; cl++) part[r][cl] = 0.0f;
#pragma unroll
    for (int p = 0; p < 4; p++) {
        const int hcol = (4 * w + p) * 16 + l15;
        const int lpbase = 16 * ((hcol >> 3) & 3);
        const int kofs = (hcol >> 5) * 64;
#pragma unroll
        for (int r = 0; r < 4; r++) {
            int m = quad * 4 + r;
            unsigned int hu = Af[(kofs + m + lpbase) * 8 + (hcol & 7)];
            union { unsigned int u; float f; } cv; cv.u = hu << 16;
            float hh = cv.f;
#pragma unroll
            for (int cl = 0; cl < 10; cl++)
                part[r][cl] += hh * Wph[hcol * 10 + cl];
        }
    }
#pragma unroll
    for (int off = 1; off < 16; off <<= 1)
#pragma unroll
        for (int r = 0; r < 4; r++)
#pragma unroll
            for (int cl = 0; cl < 10; cl++)
                part[r][cl] += __shfl_xor(part[r][cl], off, 64);

    if (tid < MB * 10) outacc[tid] = 0.0f;
    __syncthreads();
    if (l15 == 0) {
#pragma unroll
        for (int r = 0; r < 4; r++) {
            int m = quad * 4 + r;
#pragma unroll
            for (int cl = 0; cl < 10; cl++)
                atomicAdd(&outacc[m * 10 + cl], part[r][cl]);
        }
    }
    __syncthreads();
    if (tid < MB * 10) {
        int m = tid / 10, cl = tid - m * 10;
        out[(blk * MB + m) * 10 + cl] = outacc[tid] + bp[cl];
    }
}

extern "C" void kernel_launch(void* const* d_in, const int* in_sizes, int n_in,
                              void* d_out, int out_size, void* d_ws, size_t ws_size,
                              hipStream_t stream) {
    const int*   x    = (const int*)  d_in[0];
    const float* emb  = (const float*)d_in[1];
    const float* Wgx  = (const float*)d_in[2];
    const float* Wgh  = (const float*)d_in[3];
    const float* bg   = (const float*)d_in[4];
    const float* Wix  = (const float*)d_in[5];
    const float* Wih  = (const float*)d_in[6];
    const float* bi   = (const float*)d_in[7];
    const float* Wfx  = (const float*)d_in[8];
    const float* Wfh  = (const float*)d_in[9];
    const float* bf_  = (const float*)d_in[10];
    const float* Wox  = (const float*)d_in[11];
    const float* Woh  = (const float*)d_in[12];
    const float* bo   = (const float*)d_in[13];
    const float* Wph  = (const float*)d_in[14];
    const float* bp   = (const float*)d_in[15];

    unsigned short* wswz = (unsigned short*)d_ws;  // 9*64*64*16 = 576 KB

    build_wswz<<<NBLK * NKIT, 64, 0, stream>>>(Wgx, Wgh, bg, Wix, Wih, bi,
                                               Wfx, Wfh, bf_, Wox, Woh, bo, wswz);
    lstm_main<<<NBLK, 256, 0, stream>>>(x, emb, Wph, bp, wswz, (float*)d_out);
}

// Round 12
// 1601.154 us; speedup vs baseline: 1.3284x; 1.3284x over previous
//
#include <hip/hip_runtime.h>
#include <stdint.h>

#define T_STEPS 256
#define EMBD 10
#define MB 16          // batch rows per block
#define NBLK 64        // 1024 / MB
#define NKIT 9         // K = 288 = 9 * 32 (256 h + 10 x + 1 bias + pad)

typedef __attribute__((ext_vector_type(8))) short bf16x8;
typedef __attribute__((ext_vector_type(4))) float f32x4;
typedef __attribute__((ext_vector_type(4))) int   i32x4;

__device__ __forceinline__ unsigned short f2bf(float f) {
    union { float f; unsigned int u; } v; v.f = f;
    unsigned int u = v.u;
    unsigned int r = (u + 0x7FFFu + ((u >> 16) & 1u)) >> 16;  // RNE
    return (unsigned short)r;
}
__device__ __forceinline__ float sig_fast(float x) {
    return __frcp_rn(1.0f + exp2f(-1.4426950408889634f * x));
}
__device__ __forceinline__ float tanh_fast(float x) {
    return 1.0f - 2.0f * __frcp_rn(exp2f(2.8853900817779268f * x) + 1.0f);
}

// Park a frag in AGPRs -- storage the VGPR allocator cannot restream
// (R2/R4/R6/R8 restreamed every VGPR-resident plan at ~30 B/cyc/CU).
// Correctness of this park/unpark pair is HW-proven (R11 passed).
__device__ __forceinline__ i32x4 park_agpr(i32x4 v) {
    i32x4 r;
    asm volatile("v_accvgpr_write_b32 %0, %4\n\t"
                 "v_accvgpr_write_b32 %1, %5\n\t"
                 "v_accvgpr_write_b32 %2, %6\n\t"
                 "v_accvgpr_write_b32 %3, %7"
                 : "=a"(r.x), "=a"(r.y), "=a"(r.z), "=a"(r.w)
                 : "v"(v.x), "v"(v.y), "v"(v.z), "v"(v.w));
    return r;
}
__device__ __forceinline__ i32x4 unpark_agpr(i32x4 a) {
    i32x4 r;
    asm("v_accvgpr_read_b32 %0, %4\n\t"
        "v_accvgpr_read_b32 %1, %5\n\t"
        "v_accvgpr_read_b32 %2, %6\n\t"
        "v_accvgpr_read_b32 %3, %7\n\t"
        "s_nop 1"
        : "=v"(r.x), "=v"(r.y), "=v"(r.z), "=v"(r.w)
        : "a"(a.x), "a"(a.y), "a"(a.z), "a"(a.w));
    return r;
}
__device__ __forceinline__ f32x4 mfma_v(i32x4 a, i32x4 b, f32x4 c) {
    return __builtin_amdgcn_mfma_f32_16x16x32_bf16(
        __builtin_bit_cast(bf16x8, a), __builtin_bit_cast(bf16x8, b), c, 0, 0, 0);
}

// ---------------------------------------------------------------------------
// K1: swizzled bf16 weights Wfull[288][1024] in MFMA B-frag order.
// Layout: [kit 0..8][ntile 0..63][lane 0..63] x 16B.
// Lane's 8 bf16: Wfull[k = kit*32 + (lane>>4)*8 + j][n = ntile*16 + (lane&15)]
// k<256 -> Wh[k][:], 256..265 -> Wx[k-256][:], 266 -> bias, else 0.
// ---------------------------------------------------------------------------
__global__ __launch_bounds__(64) void build_wswz(
    const float* __restrict__ Wgx, const float* __restrict__ Wgh, const float* __restrict__ bg,
    const float* __restrict__ Wix, const float* __restrict__ Wih, const float* __restrict__ bi,
    const float* __restrict__ Wfx, const float* __restrict__ Wfh, const float* __restrict__ bf_,
    const float* __restrict__ Wox, const float* __restrict__ Woh, const float* __restrict__ bo,
    unsigned short* __restrict__ wswz)
{
    int g   = blockIdx.x / NKIT;   // ntile
    int kit = blockIdx.x % NKIT;
    int lane = threadIdx.x;
    int n = g * 16 + (lane & 15);
    int q = n >> 8;
    int col = n & 255;
    const float* Wh = (q == 0) ? Wgh : (q == 1) ? Wih : (q == 2) ? Wfh : Woh;
    const float* Wx = (q == 0) ? Wgx : (q == 1) ? Wix : (q == 2) ? Wfx : Wox;
    const float* bb = (q == 0) ? bg  : (q == 1) ? bi  : (q == 2) ? bf_ : bo;
    int k0 = kit * 32 + (lane >> 4) * 8;

    int4 out;
    unsigned short* p = (unsigned short*)&out;
#pragma unroll
    for (int j = 0; j < 8; j++) {
        int k = k0 + j;
        float v = 0.0f;
        if (k < 256)             v = Wh[k * 256 + col];
        else if (k < 256 + EMBD) v = Wx[(k - 256) * 256 + col];
        else if (k == 266)       v = bb[col];
        p[j] = f2bf(v);
    }
    ((int4*)wswz)[(kit * 64 + g) * 64 + lane] = out;
}

// ---------------------------------------------------------------------------
// K2: persistent LSTM. 64 blocks x 512 threads (8 waves, 2 waves/SIMD --
// latency hiding proven in R4; 1/SIMD was latency-bound, R11).
// Wave w owns hcols 32w+16u+l15 (u=0,1) x 4 gates: nt = gate*16 + 2w + u.
// B residency/wave: kits {0,1,2,3} PARKED in AGPRs (32 frags = 128 AGPR,
// immune to allocator restream), kits {5,6} in LDS (128 KB), kits {4,7,8}
// streamed (kit 8 half: B-frags zero for lanes>=32 -> predicated 512B loads)
// = 160 KB/step/CU (vs R4's 448). Single 12-frag landing buffer with
// consume-then-reissue: addresses are t-invariant, so pass u=1 prefetches
// next step's u=0 across the barrier -> >=1 pass of latency cover per load.
// ---------------------------------------------------------------------------
__global__ __launch_bounds__(512)
__attribute__((amdgpu_waves_per_eu(2, 2)))
void lstm_main(
    const int*   __restrict__ xtok,   // [1024][1][256]
    const float* __restrict__ emb,    // [32000][10]
    const float* __restrict__ Wph,    // [256][10]
    const float* __restrict__ bp,     // [10]
    const unsigned short* __restrict__ wswz,
    float* __restrict__ out)          // [1024][10]
{
    __shared__ __align__(16) unsigned short A_lds[2][8 * 64 * 8];   // 16 KB (kits 0-7)
    __shared__ __align__(16) unsigned short A8_lds[2][64 * 8];      // 2 KB (kit 8)
    __shared__ __align__(16) i32x4 B_lds[2 * 64 * 64];              // 128 KB (kits 5,6)
    __shared__ float outacc[MB * 10];

    const int tid  = threadIdx.x;
    const int w    = tid >> 6;        // wave 0..7
    const int lane = tid & 63;
    const int quad = lane >> 4;
    const int l15  = lane & 15;
    const int blk  = blockIdx.x;

    const int m_x = tid >> 4;         // x-gather: batch row 0..15 (tid<256)
    const int e_x = tid & 15;         // emb element (valid if <10)

    const i32x4* Bg = (const i32x4*)wswz;

    // --- prologue: LDS B-cache (kits 5,6) ---
    for (int i = tid; i < 2 * 64 * 64; i += 512)
        B_lds[i] = Bg[5 * 4096 + i];

    // --- AGPR-parked B: kits 0..3, [kit][gate][u] = 32 frags = 128 AGPR ---
    i32x4 bag[4][4][2];
#pragma unroll
    for (int s = 0; s < 4; s++)
#pragma unroll
        for (int g = 0; g < 4; g++)
#pragma unroll
            for (int u = 0; u < 2; u++)
                bag[s][g][u] = park_agpr(
                    Bg[(s * 64 + g * 16 + 2 * w + u) * 64 + lane]);

    // --- streamed landing buffer: kits 4 (0..3), 7 (4..7), 8 (8..11) ---
    i32x4 land[12];
#pragma unroll
    for (int g = 0; g < 4; g++) {
        land[g]     = Bg[(4 * 64 + g * 16 + 2 * w) * 64 + lane];
        land[4 + g] = Bg[(7 * 64 + g * 16 + 2 * w) * 64 + lane];
        land[8 + g] = (i32x4){0, 0, 0, 0};
        if (lane < 32)
            land[8 + g] = Bg[(8 * 64 + g * 16 + 2 * w) * 64 + lane];
    }

    // --- init A double buffer: zeros, bias row (both), x_0 (buf 0) ---
    {
        int4 z4 = {0, 0, 0, 0};
        for (int i = tid; i < 1024; i += 512) ((int4*)A_lds)[i] = z4;
        if (tid < 128) ((int4*)A8_lds)[tid] = z4;
    }
    __syncthreads();
    if (tid < 16) {
        // kit8 local k=10 (bias=1.0): lp = m+16, elem 2
        A8_lds[0][(16 + tid) * 8 + 2] = 0x3F80;
        A8_lds[1][(16 + tid) * 8 + 2] = 0x3F80;
    }
    if (tid < 256 && e_x < EMBD) {
        int tok = xtok[(blk * MB + m_x) * T_STEPS + 0];
        float v = emb[tok * EMBD + e_x];
        A8_lds[0][(m_x + 16 * (e_x >> 3)) * 8 + (e_x & 7)] = f2bf(v);
    }
    __syncthreads();

    float c[2][4];
#pragma unroll
    for (int u = 0; u < 2; u++)
#pragma unroll
        for (int r = 0; r < 4; r++) c[u][r] = 0.0f;

    for (int t = 0; t < T_STEPS; t++) {
        const i32x4* Ab  = (const i32x4*)A_lds[t & 1];
        const i32x4* A8b = (const i32x4*)A8_lds[t & 1];
        unsigned short* Aw  = A_lds[(t + 1) & 1];
        unsigned short* A8w = A8_lds[(t + 1) & 1];

        // x(t+1) prefetch (independent; overlaps MFMA)
        float xval = 0.0f;
        const bool do_x = (t < T_STEPS - 1) && (tid < 256) && (e_x < EMBD);
        if ((t < T_STEPS - 1) && (tid < 256)) {
            int tok = xtok[(blk * MB + m_x) * T_STEPS + (t + 1)];
            if (e_x < EMBD) xval = emb[tok * EMBD + e_x];
        }

#pragma unroll
        for (int u = 0; u < 2; u++) {
            const int nu = 1 - u;  // reissue target (t-invariant addresses)

            // A-frag window (3 deep), kit-use order 0,1,2,3,5,6,4,7,8
            i32x4 a0 = Ab[0 * 64 + lane];
            i32x4 a1 = Ab[1 * 64 + lane];
            i32x4 a2 = Ab[2 * 64 + lane];

            f32x4 acc[4];
#pragma unroll
            for (int g = 0; g < 4; g++) acc[g] = (f32x4){0.f, 0.f, 0.f, 0.f};

            // kits 0..3 from AGPR (unpark per use)
#pragma unroll
            for (int g = 0; g < 4; g++)
                acc[g] = mfma_v(a0, unpark_agpr(bag[0][g][u]), acc[g]);
            a0 = Ab[3 * 64 + lane];
#pragma unroll
            for (int g = 0; g < 4; g++)
                acc[g] = mfma_v(a1, unpark_agpr(bag[1][g][u]), acc[g]);
            a1 = Ab[5 * 64 + lane];
#pragma unroll
            for (int g = 0; g < 4; g++)
                acc[g] = mfma_v(a2, unpark_agpr(bag[2][g][u]), acc[g]);
            a2 = Ab[6 * 64 + lane];
#pragma unroll
            for (int g = 0; g < 4; g++)
                acc[g] = mfma_v(a0, unpark_agpr(bag[3][g][u]), acc[g]);
            a0 = Ab[4 * 64 + lane];
            // kit 5 (LDS)
#pragma unroll
            for (int g = 0; g < 4; g++)
                acc[g] = mfma_v(a1, B_lds[(g * 16 + 2 * w + u) * 64 + lane], acc[g]);
            a1 = Ab[7 * 64 + lane];
            // kit 6 (LDS)
#pragma unroll
            for (int g = 0; g < 4; g++)
                acc[g] = mfma_v(a2, B_lds[4096 + (g * 16 + 2 * w + u) * 64 + lane], acc[g]);
            a2 = A8b[lane];
            // kit 4 (streamed) -> consume, then reissue for next pass
#pragma unroll
            for (int g = 0; g < 4; g++)
                acc[g] = mfma_v(a0, land[g], acc[g]);
#pragma unroll
            for (int g = 0; g < 4; g++)
                land[g] = Bg[(4 * 64 + g * 16 + 2 * w + nu) * 64 + lane];
            // kit 7 (streamed)
#pragma unroll
            for (int g = 0; g < 4; g++)
                acc[g] = mfma_v(a1, land[4 + g], acc[g]);
#pragma unroll
            for (int g = 0; g < 4; g++)
                land[4 + g] = Bg[(7 * 64 + g * 16 + 2 * w + nu) * 64 + lane];
            // kit 8 (streamed, half-frag: lanes>=32 are zero)
#pragma unroll
            for (int g = 0; g < 4; g++)
                acc[g] = mfma_v(a2, land[8 + g], acc[g]);
#pragma unroll
            for (int g = 0; g < 4; g++) {
                i32x4 v = (i32x4){0, 0, 0, 0};
                if (lane < 32)
                    v = Bg[(8 * 64 + g * 16 + 2 * w + nu) * 64 + lane];
                land[8 + g] = v;
            }

            // gate math: z[m][n], m = quad*4+r, n = gate*256 + 32w + 16u + l15
            const int hcol = 32 * w + 16 * u + l15;
            const int lpbase = 16 * ((hcol >> 3) & 3);
#pragma unroll
            for (int r = 0; r < 4; r++) {
                float gg = tanh_fast(acc[0][r]);
                float ii = sig_fast(acc[1][r]);
                float ff = sig_fast(acc[2][r]);
                float oo = sig_fast(acc[3][r]);
                float cn = gg * ii + c[u][r] * ff;
                c[u][r] = cn;
                float hh = tanh_fast(cn) * oo;
                int m = quad * 4 + r;
                Aw[(w * 64 + m + lpbase) * 8 + (hcol & 7)] = f2bf(hh);
            }
        }
        if (t == T_STEPS - 1) break;
        if (do_x)
            A8w[(m_x + 16 * (e_x >> 3)) * 8 + (e_x & 7)] = f2bf(xval);
        __syncthreads();  // single barrier: A(t+1) complete
    }
    __syncthreads();

    // --- epilogue: re-read own h (bf16) from final A buffer, project ---
    const unsigned short* Af = A_lds[T_STEPS & 1];
    float part[4][10];
#pragma unroll
    for (int r = 0; r < 4; r++)
#pragma unroll
        for (int cl = 0; cl < 10; cl++) part[r][cl] = 0.0f;
#pragma unroll
    for (int u = 0; u < 2; u++) {
        const int hcol = 32 * w + 16 * u + l15;
        const int lpbase = 16 * ((hcol >> 3) & 3);
#pragma unroll
        for (int r = 0; r < 4; r++) {
            int m = quad * 4 + r;
            unsigned int hu = Af[(w * 64 + m + lpbase) * 8 + (hcol & 7)];
            union { unsigned int uu; float f; } cv; cv.uu = hu << 16;
            float hh = cv.f;
#pragma unroll
            for (int cl = 0; cl < 10; cl++)
                part[r][cl] += hh * Wph[hcol * 10 + cl];
        }
    }
#pragma unroll
    for (int off = 1; off < 16; off <<= 1)
#pragma unroll
        for (int r = 0; r < 4; r++)
#pragma unroll
            for (int cl = 0; cl < 10; cl++)
                part[r][cl] += __shfl_xor(part[r][cl], off, 64);

    if (tid < MB * 10) outacc[tid] = 0.0f;
    __syncthreads();
    if (l15 == 0) {
#pragma unroll
        for (int r = 0; r < 4; r++) {
            int m = quad * 4 + r;
#pragma unroll
            for (int cl = 0; cl < 10; cl++)
                atomicAdd(&outacc[m * 10 + cl], part[r][cl]);
        }
    }
    __syncthreads();
    if (tid < MB * 10) {
        int m = tid / 10, cl = tid - m * 10;
        out[(blk * MB + m) * 10 + cl] = outacc[tid] + bp[cl];
    }
}

extern "C" void kernel_launch(void* const* d_in, const int* in_sizes, int n_in,
                              void* d_out, int out_size, void* d_ws, size_t ws_size,
                              hipStream_t stream) {
    const int*   x    = (const int*)  d_in[0];
    const float* emb  = (const float*)d_in[1];
    const float* Wgx  = (const float*)d_in[2];
    const float* Wgh  = (const float*)d_in[3];
    const float* bg   = (const float*)d_in[4];
    const float* Wix  = (const float*)d_in[5];
    const float* Wih  = (const float*)d_in[6];
    const float* bi   = (const float*)d_in[7];
    const float* Wfx  = (const float*)d_in[8];
    const float* Wfh  = (const float*)d_in[9];
    const float* bf_  = (const float*)d_in[10];
    const float* Wox  = (const float*)d_in[11];
    const float* Woh  = (const float*)d_in[12];
    const float* bo   = (const float*)d_in[13];
    const float* Wph  = (const float*)d_in[14];
    const float* bp   = (const float*)d_in[15];

    unsigned short* wswz = (unsigned short*)d_ws;  // 9*64*64*16 = 576 KB

    build_wswz<<<NBLK * NKIT, 64, 0, stream>>>(Wgx, Wgh, bg, Wix, Wih, bi,
                                               Wfx, Wfh, bf_, Wox, Woh, bo, wswz);
    lstm_main<<<NBLK, 512, 0, stream>>>(x, emb, Wph, bp, wswz, (float*)d_out);
}